// Round 8
// baseline (963.143 us; speedup 1.0000x reference)
//
#include <hip/hip_runtime.h>
#include <hip/hip_bf16.h>

#define NNZ  131072
#define MT   1048576
#define EMB  128
#define NSEG 2048           // segments = io >> 6 (64 output rows each)
#define SEGSZ 64

typedef __attribute__((ext_vector_type(8))) short  short8;
typedef __attribute__((ext_vector_type(4))) float  floatx4;

__device__ __forceinline__ ushort f2bf(float f) {
    unsigned u = __float_as_uint(f);
    u = (u + 0x7FFFu + ((u >> 16) & 1u)) >> 16;   // RNE
    return (ushort)u;
}
__device__ __forceinline__ float bfl(unsigned u) { return __uint_as_float(u << 16); }
__device__ __forceinline__ float bfh(unsigned u) { return __uint_as_float(u & 0xffff0000u); }

__device__ __forceinline__ unsigned long long packE(int a, int b, int o) {
    return (unsigned long long)(unsigned)a |
           ((unsigned long long)(unsigned)b << 17) |
           ((unsigned long long)(unsigned)(o & 63) << 34);
}

// ---------------------------------------------------------------------------
// prep: blocks 0..31 pack weights into B-fragment order; blocks 32..287 build
// per-block 2048-bin histograms of io>>6 (4096 items each, LDS atomics only).
// ---------------------------------------------------------------------------
__global__ __launch_bounds__(256) void prep_kernel(
    const float* __restrict__ W10, const float* __restrict__ W11,
    const float* __restrict__ W20, const float* __restrict__ W21,
    ushort* __restrict__ Wpk, const int* __restrict__ io,
    int* __restrict__ bh)
{
    __shared__ int h[NSEG];
    const int bid = blockIdx.x, tid = threadIdx.x;

    if (bid < 32) {                          // ---- weight pack ----
        int s = bid * 256 + tid;             // 0..8191
        int L = s >> 11, sl = s & 2047;
        const float* W = (L == 0) ? W10 : (L == 1) ? W11 : (L == 2) ? W20 : W21;
        int lane = sl & 63, nk = sl >> 6;
        int col  = (nk >> 2) * 16 + (lane & 15);
        int krow = (nk & 3) * 32 + (lane >> 4) * 8;
        short8 w;
        #pragma unroll
        for (int j = 0; j < 8; ++j)
            w[j] = (short)f2bf(W[(krow + j) * EMB + col]);
        *(short8*)&Wpk[(size_t)s * 8] = w;
        return;
    }

    const int b = bid - 32;                  // 0..255
    for (int i = tid; i < NSEG; i += 256) h[i] = 0;
    __syncthreads();
    const int4* io4 = (const int4*)io + b * 1024;
    for (int j = tid; j < 1024; j += 256) {
        int4 v = io4[j];
        atomicAdd(&h[v.x >> 6], 1);
        atomicAdd(&h[v.y >> 6], 1);
        atomicAdd(&h[v.z >> 6], 1);
        atomicAdd(&h[v.w >> 6], 1);
    }
    __syncthreads();
    for (int d = tid; d < NSEG; d += 256) bh[d * 256 + b] = h[d];
}

// ---------------------------------------------------------------------------
// scan1: exclusive scan of bh[NSEG*256] (segment-major) in place; emits
// segptr[d] at d*256 boundaries and segptr[NSEG]=MT.
// ---------------------------------------------------------------------------
__global__ __launch_bounds__(1024) void scan1_kernel(
    int* __restrict__ bh, int* __restrict__ segptr)
{
    __shared__ int part[1024];
    int tid = threadIdx.x;
    int4* c4 = (int4*)(bh + tid * 512);      // 2 segments per thread
    int s = 0;
    #pragma unroll 8
    for (int j = 0; j < 128; ++j) { int4 v = c4[j]; s += v.x + v.y + v.z + v.w; }
    part[tid] = s;
    __syncthreads();
    for (int off = 1; off < 1024; off <<= 1) {
        int v = (tid >= off) ? part[tid - off] : 0;
        __syncthreads();
        part[tid] += v;
        __syncthreads();
    }
    int run = part[tid] - s;                 // exclusive prefix at tid*512
    segptr[tid * 2] = run;
    #pragma unroll 8
    for (int j = 0; j < 128; ++j) {
        if (j == 64) segptr[tid * 2 + 1] = run;
        int4 v = c4[j]; int4 w;
        w.x = run; run += v.x;
        w.y = run; run += v.y;
        w.z = run; run += v.z;
        w.w = run; run += v.w;
        c4[j] = w;
    }
    if (tid == 1023) segptr[NSEG] = run;     // = MT
}

// ---------------------------------------------------------------------------
// Union: grid 2304 x 256. blockIdx%9==0 -> seg_scatter (256 blocks, LDS rank
// claim from scanned bases, zero global atomics); else -> mlp (2048 blocks).
// ---------------------------------------------------------------------------
__global__ __launch_bounds__(256, 3) void union_kernel(
    const float* __restrict__ Xv, const ushort* __restrict__ Wpk,
    const float* __restrict__ b10, const float* __restrict__ b11,
    const float* __restrict__ b20, const float* __restrict__ b21,
    ushort* __restrict__ X1b, ushort* __restrict__ X2b,
    const int* __restrict__ io, const int* __restrict__ ia,
    const int* __restrict__ ib, const int* __restrict__ bh,
    unsigned long long* __restrict__ srt)
{
    __shared__ ushort Wp[16384];           // 32 KB (scatter aliases 8 KB)
    __shared__ ushort Hs[8192];            // 16 KB

    const int bid = blockIdx.x;
    const int tid = threadIdx.x;
    const int q   = bid / 9;

    if (bid - q * 9 == 0) {                // ---- scatter role (block q) ----
        int* cur = (int*)Wp;               // 2048 ints
        for (int d = tid; d < NSEG; d += 256) cur[d] = bh[d * 256 + q];
        __syncthreads();
        const int4* io4 = (const int4*)io + q * 1024;
        const int4* ia4 = (const int4*)ia + q * 1024;
        const int4* ib4 = (const int4*)ib + q * 1024;
        for (int j = tid; j < 1024; j += 256) {
            int4 o = io4[j], a = ia4[j], c = ib4[j];
            int p;
            p = atomicAdd(&cur[o.x >> 6], 1); srt[p] = packE(a.x, c.x, o.x);
            p = atomicAdd(&cur[o.y >> 6], 1); srt[p] = packE(a.y, c.y, o.y);
            p = atomicAdd(&cur[o.z >> 6], 1); srt[p] = packE(a.z, c.z, o.z);
            p = atomicAdd(&cur[o.w >> 6], 1); srt[p] = packE(a.w, c.w, o.w);
        }
        return;
    }

    // ---- mlp role ----
    const int mid  = bid - q - 1;          // dense 0..2047
    const int wave = tid >> 6;
    const int lane = tid & 63;
    const int g    = lane >> 4;
    const int r    = lane & 15;
    const int rowbase = mid * 64 + wave * 16;
    char* hw = (char*)(Hs + wave * 2048);

    short8 af[4];
    {
        const float* xsrc = Xv + (size_t)(rowbase + r) * EMB;
        #pragma unroll
        for (int kt = 0; kt < 4; ++kt) {
            const float4* p = (const float4*)(xsrc + kt * 32 + g * 8);
            float4 v0 = p[0], v1 = p[1];
            short8 a;
            a[0] = (short)f2bf(v0.x); a[1] = (short)f2bf(v0.y);
            a[2] = (short)f2bf(v0.z); a[3] = (short)f2bf(v0.w);
            a[4] = (short)f2bf(v1.x); a[5] = (short)f2bf(v1.y);
            a[6] = (short)f2bf(v1.z); a[7] = (short)f2bf(v1.w);
            af[kt] = a;
        }
    }

    auto stageW = [&](int L) {
        const ushort* src = Wpk + (size_t)L * 16384;
        #pragma unroll
        for (int s = tid; s < 2048; s += 256)
            *(short8*)&Wp[s * 8] = *(const short8*)&src[(size_t)s * 8];
    };

    floatx4 acc[8];
    auto runMFMA = [&](const short8* a4) {
        #pragma unroll
        for (int n = 0; n < 8; ++n) {
            floatx4 c = {0.f, 0.f, 0.f, 0.f};
            #pragma unroll
            for (int kt = 0; kt < 4; ++kt) {
                short8 b = *(const short8*)&Wp[((n * 4 + kt) * 64 + lane) * 8];
                c = __builtin_amdgcn_mfma_f32_16x16x32_bf16(b, a4[kt], c, 0, 0, 0);
            }
            acc[n] = c;
        }
    };

    auto epi = [&](const float* __restrict__ bias) {
        #pragma unroll
        for (int n = 0; n < 8; ++n) {
            float4 bv = *(const float4*)&bias[n * 16 + g * 4];
            ushort4 w;
            w.x = f2bf(fmaxf(acc[n][0] + bv.x, 0.f));
            w.y = f2bf(fmaxf(acc[n][1] + bv.y, 0.f));
            w.z = f2bf(fmaxf(acc[n][2] + bv.z, 0.f));
            w.w = f2bf(fmaxf(acc[n][3] + bv.w, 0.f));
            int byte = r * 256 + n * 32 + g * 8;
            byte ^= ((r & 3) << 5) ^ ((r & 4) << 2);
            *(ushort4*)(hw + byte) = w;
        }
    };

    auto loadH = [&](short8* h4) {
        #pragma unroll
        for (int kt = 0; kt < 4; ++kt) {
            int byte = r * 256 + kt * 64 + g * 16;
            byte ^= ((r & 3) << 5) ^ ((r & 4) << 2);
            h4[kt] = *(const short8*)(hw + byte);
        }
    };

    auto storeG = [&](ushort* __restrict__ dst) {
        #pragma unroll
        for (int it = 0; it < 4; ++it) {
            int row  = it * 4 + g;
            int byte = row * 256 + (lane & 15) * 16;
            byte ^= ((row & 3) << 5) ^ ((row & 4) << 2);
            short8 v = *(const short8*)(hw + byte);
            *(short8*)&dst[(size_t)rowbase * EMB + row * EMB + (lane & 15) * 8] = v;
        }
    };

    short8 h4[4];

    stageW(0); __syncthreads();
    runMFMA(af); epi(b10); __syncthreads();
    stageW(1); loadH(h4); __syncthreads();
    runMFMA(h4); epi(b11); __syncthreads();
    stageW(2); storeG(X1b); __syncthreads();
    runMFMA(af); epi(b20); __syncthreads();
    stageW(3); loadH(h4); __syncthreads();
    runMFMA(h4); epi(b21); __syncthreads();
    storeG(X2b);
}

// ---------------------------------------------------------------------------
// gather_seg: one block per segment (64 rows). 32 KB LDS f32 accumulators,
// entries processed in arbitrary order with 8-deep in-flight row loads,
// ds_add_f32 accumulation ([row][plane][lane] -> 2-way banks = free),
// coalesced float4 output (full 64x128 coverage via 2 passes).
// ---------------------------------------------------------------------------
__global__ __launch_bounds__(1024, 4) void gather_seg(
    const ushort* __restrict__ X1b, const ushort* __restrict__ X2b,
    const unsigned long long* __restrict__ srt, const int* __restrict__ segptr,
    float* __restrict__ out)
{
    __shared__ float acc[SEGSZ][2][64];    // 32 KB
    const int s   = blockIdx.x;
    const int tid = threadIdx.x;
    const int wv  = tid >> 6, lane = tid & 63;

    float4 z4 = {0.f, 0.f, 0.f, 0.f};
    ((float4*)acc)[tid * 2]     = z4;
    ((float4*)acc)[tid * 2 + 1] = z4;
    __syncthreads();

    const int beg = segptr[s], end = segptr[s + 1];
    const int n = end - beg;
    const unsigned* x1 = (const unsigned*)X1b + lane;
    const unsigned* x2 = (const unsigned*)X2b + lane;

    for (int c = wv * 8; c < n; c += 128) {
        int m = n - c; if (m > 8) m = 8;
        unsigned long long E[8];
        #pragma unroll
        for (int e = 0; e < 8; ++e)
            E[e] = srt[beg + c + (e < m ? e : 0)];
        #pragma unroll
        for (int e = 0; e < 8; ++e) {
            unsigned u1 = x1[(unsigned)(E[e] & 0x1FFFF) * 64u];
            unsigned u2 = x2[(unsigned)((E[e] >> 17) & 0x1FFFF) * 64u];
            int ro = (int)(E[e] >> 34);
            if (e >= m) u1 = 0u;
            atomicAdd(&acc[ro][0][lane], bfl(u1) * bfl(u2));
            atomicAdd(&acc[ro][1][lane], bfh(u1) * bfh(u2));
        }
    }
    __syncthreads();

    // full coverage: 2048 virtual threads x float4 = 64 rows x 128 cols
    #pragma unroll
    for (int h = 0; h < 2; ++h) {
        int t   = tid + h * 1024;          // 0..2047
        int row = t >> 5, qq = t & 31;     // col base = qq*4
        float4 v;
        v.x = acc[row][0][2 * qq];
        v.y = acc[row][1][2 * qq];
        v.z = acc[row][0][2 * qq + 1];
        v.w = acc[row][1][2 * qq + 1];
        *(float4*)(out + ((size_t)s * SEGSZ + row) * EMB + qq * 4) = v;
    }
}

// ---------------------------------------------------------------------------
extern "C" void kernel_launch(void* const* d_in, const int* in_sizes, int n_in,
                              void* d_out, int out_size, void* d_ws, size_t ws_size,
                              hipStream_t stream)
{
    (void)in_sizes; (void)n_in; (void)out_size; (void)ws_size;

    const float* Xv  = (const float*)d_in[0];
    const float* W10 = (const float*)d_in[1];
    const float* b10 = (const float*)d_in[2];
    const float* W11 = (const float*)d_in[3];
    const float* b11 = (const float*)d_in[4];
    const float* W20 = (const float*)d_in[5];
    const float* b20 = (const float*)d_in[6];
    const float* W21 = (const float*)d_in[7];
    const float* b21 = (const float*)d_in[8];
    const int*   ia  = (const int*)d_in[9];
    const int*   ib  = (const int*)d_in[10];
    const int*   io  = (const int*)d_in[11];
    float* out = (float*)d_out;

    char* ws = (char*)d_ws;
    ushort*             X1b    = (ushort*)(ws);                 // 32 MB
    ushort*             X2b    = (ushort*)(ws + 33554432);      // 32 MB
    ushort*             Wpk    = (ushort*)(ws + 67108864);      // 256 KB
    int*                bh     = (int*)(ws + 67371008);         // 2 MB
    int*                segptr = (int*)(ws + 69468160);         // 8.2 KB
    unsigned long long* srt    = (unsigned long long*)(ws + 69476864); // 8 MB

    prep_kernel<<<288, 256, 0, stream>>>(W10, W11, W20, W21, Wpk, io, bh);
    scan1_kernel<<<1, 1024, 0, stream>>>(bh, segptr);
    union_kernel<<<2304, 256, 0, stream>>>(Xv, Wpk, b10, b11, b20, b21,
                                           X1b, X2b, io, ia, ib, bh, srt);
    gather_seg<<<NSEG, 1024, 0, stream>>>(X1b, X2b, srt, segptr, out);
}

// Round 9
// 377.429 us; speedup vs baseline: 2.5519x; 2.5519x over previous
//
#include <hip/hip_runtime.h>
#include <hip/hip_bf16.h>

#define NNZ  131072
#define MT   1048576
#define EMB  128
#define NSEG 2048           // segments = io >> 6 (64 output rows each)
#define SEGSZ 64
#define ENTCAP 1024         // staged entries per segment (mean 512, +22 sigma)

typedef __attribute__((ext_vector_type(8))) short  short8;
typedef __attribute__((ext_vector_type(4))) float  floatx4;

__device__ __forceinline__ ushort f2bf(float f) {
    unsigned u = __float_as_uint(f);
    u = (u + 0x7FFFu + ((u >> 16) & 1u)) >> 16;   // RNE
    return (ushort)u;
}
__device__ __forceinline__ float bfl(unsigned u) { return __uint_as_float(u << 16); }
__device__ __forceinline__ float bfh(unsigned u) { return __uint_as_float(u & 0xffff0000u); }

__device__ __forceinline__ unsigned long long packE(int a, int b, int o) {
    return (unsigned long long)(unsigned)a |
           ((unsigned long long)(unsigned)b << 17) |
           ((unsigned long long)(unsigned)(o & 63) << 34);
}

// ---------------------------------------------------------------------------
// prep: blocks 0..31 pack weights; blocks 32..287 per-block 2048-bin
// histograms of io>>6 (4096 items each, LDS int atomics).
// ---------------------------------------------------------------------------
__global__ __launch_bounds__(256) void prep_kernel(
    const float* __restrict__ W10, const float* __restrict__ W11,
    const float* __restrict__ W20, const float* __restrict__ W21,
    ushort* __restrict__ Wpk, const int* __restrict__ io,
    int* __restrict__ bh)
{
    __shared__ int h[NSEG];
    const int bid = blockIdx.x, tid = threadIdx.x;

    if (bid < 32) {                          // ---- weight pack ----
        int s = bid * 256 + tid;             // 0..8191
        int L = s >> 11, sl = s & 2047;
        const float* W = (L == 0) ? W10 : (L == 1) ? W11 : (L == 2) ? W20 : W21;
        int lane = sl & 63, nk = sl >> 6;
        int col  = (nk >> 2) * 16 + (lane & 15);
        int krow = (nk & 3) * 32 + (lane >> 4) * 8;
        short8 w;
        #pragma unroll
        for (int j = 0; j < 8; ++j)
            w[j] = (short)f2bf(W[(krow + j) * EMB + col]);
        *(short8*)&Wpk[(size_t)s * 8] = w;
        return;
    }

    const int b = bid - 32;                  // 0..255
    for (int i = tid; i < NSEG; i += 256) h[i] = 0;
    __syncthreads();
    const int4* io4 = (const int4*)io + b * 1024;
    for (int j = tid; j < 1024; j += 256) {
        int4 v = io4[j];
        atomicAdd(&h[v.x >> 6], 1);
        atomicAdd(&h[v.y >> 6], 1);
        atomicAdd(&h[v.z >> 6], 1);
        atomicAdd(&h[v.w >> 6], 1);
    }
    __syncthreads();
    for (int d = tid; d < NSEG; d += 256) bh[d * 256 + b] = h[d];
}

// ---------------------------------------------------------------------------
// scan1: exclusive scan of bh[NSEG*256] (segment-major) in place; emits
// segptr[d] at d*256 boundaries and segptr[NSEG]=MT.
// ---------------------------------------------------------------------------
__global__ __launch_bounds__(1024) void scan1_kernel(
    int* __restrict__ bh, int* __restrict__ segptr)
{
    __shared__ int part[1024];
    int tid = threadIdx.x;
    int4* c4 = (int4*)(bh + tid * 512);      // 2 segments per thread
    int s = 0;
    #pragma unroll 8
    for (int j = 0; j < 128; ++j) { int4 v = c4[j]; s += v.x + v.y + v.z + v.w; }
    part[tid] = s;
    __syncthreads();
    for (int off = 1; off < 1024; off <<= 1) {
        int v = (tid >= off) ? part[tid - off] : 0;
        __syncthreads();
        part[tid] += v;
        __syncthreads();
    }
    int run = part[tid] - s;                 // exclusive prefix at tid*512
    segptr[tid * 2] = run;
    #pragma unroll 8
    for (int j = 0; j < 128; ++j) {
        if (j == 64) segptr[tid * 2 + 1] = run;
        int4 v = c4[j]; int4 w;
        w.x = run; run += v.x;
        w.y = run; run += v.y;
        w.z = run; run += v.z;
        w.w = run; run += v.w;
        c4[j] = w;
    }
    if (tid == 1023) segptr[NSEG] = run;     // = MT
}

// ---------------------------------------------------------------------------
// Union: grid 2080 x 256. blockIdx%65==0 -> seg_scatter (32 blocks, each
// covers 8 hist-blocks = 32768 items; slices per segment ~16 entries = 128B
// contiguous -> line-granular srt writes); else -> mlp (2048 blocks).
// ---------------------------------------------------------------------------
__global__ __launch_bounds__(256, 3) void union_kernel(
    const float* __restrict__ Xv, const ushort* __restrict__ Wpk,
    const float* __restrict__ b10, const float* __restrict__ b11,
    const float* __restrict__ b20, const float* __restrict__ b21,
    ushort* __restrict__ X1b, ushort* __restrict__ X2b,
    const int* __restrict__ io, const int* __restrict__ ia,
    const int* __restrict__ ib, const int* __restrict__ bh,
    unsigned long long* __restrict__ srt)
{
    __shared__ ushort Wp[16384];           // 32 KB (scatter aliases 8 KB)
    __shared__ ushort Hs[8192];            // 16 KB

    const int bid = blockIdx.x;
    const int tid = threadIdx.x;
    const int q   = bid / 65;

    if (bid == q * 65) {                   // ---- scatter role (q in 0..31) ----
        int* cur = (int*)Wp;               // 2048 ints
        for (int d = tid; d < NSEG; d += 256) cur[d] = bh[d * 256 + q * 8];
        __syncthreads();
        const int4* io4 = (const int4*)io + q * 8192;
        const int4* ia4 = (const int4*)ia + q * 8192;
        const int4* ib4 = (const int4*)ib + q * 8192;
        for (int j = tid; j < 8192; j += 256) {
            int4 o = io4[j], a = ia4[j], c = ib4[j];
            int p;
            p = atomicAdd(&cur[o.x >> 6], 1); srt[p] = packE(a.x, c.x, o.x);
            p = atomicAdd(&cur[o.y >> 6], 1); srt[p] = packE(a.y, c.y, o.y);
            p = atomicAdd(&cur[o.z >> 6], 1); srt[p] = packE(a.z, c.z, o.z);
            p = atomicAdd(&cur[o.w >> 6], 1); srt[p] = packE(a.w, c.w, o.w);
        }
        return;
    }

    // ---- mlp role ----
    const int mid  = bid - q - 1;          // dense 0..2047
    const int wave = tid >> 6;
    const int lane = tid & 63;
    const int g    = lane >> 4;
    const int r    = lane & 15;
    const int rowbase = mid * 64 + wave * 16;
    char* hw = (char*)(Hs + wave * 2048);

    short8 af[4];
    {
        const float* xsrc = Xv + (size_t)(rowbase + r) * EMB;
        #pragma unroll
        for (int kt = 0; kt < 4; ++kt) {
            const float4* p = (const float4*)(xsrc + kt * 32 + g * 8);
            float4 v0 = p[0], v1 = p[1];
            short8 a;
            a[0] = (short)f2bf(v0.x); a[1] = (short)f2bf(v0.y);
            a[2] = (short)f2bf(v0.z); a[3] = (short)f2bf(v0.w);
            a[4] = (short)f2bf(v1.x); a[5] = (short)f2bf(v1.y);
            a[6] = (short)f2bf(v1.z); a[7] = (short)f2bf(v1.w);
            af[kt] = a;
        }
    }

    auto stageW = [&](int L) {
        const ushort* src = Wpk + (size_t)L * 16384;
        #pragma unroll
        for (int s = tid; s < 2048; s += 256)
            *(short8*)&Wp[s * 8] = *(const short8*)&src[(size_t)s * 8];
    };

    floatx4 acc[8];
    auto runMFMA = [&](const short8* a4) {
        #pragma unroll
        for (int n = 0; n < 8; ++n) {
            floatx4 c = {0.f, 0.f, 0.f, 0.f};
            #pragma unroll
            for (int kt = 0; kt < 4; ++kt) {
                short8 b = *(const short8*)&Wp[((n * 4 + kt) * 64 + lane) * 8];
                c = __builtin_amdgcn_mfma_f32_16x16x32_bf16(b, a4[kt], c, 0, 0, 0);
            }
            acc[n] = c;
        }
    };

    auto epi = [&](const float* __restrict__ bias) {
        #pragma unroll
        for (int n = 0; n < 8; ++n) {
            float4 bv = *(const float4*)&bias[n * 16 + g * 4];
            ushort4 w;
            w.x = f2bf(fmaxf(acc[n][0] + bv.x, 0.f));
            w.y = f2bf(fmaxf(acc[n][1] + bv.y, 0.f));
            w.z = f2bf(fmaxf(acc[n][2] + bv.z, 0.f));
            w.w = f2bf(fmaxf(acc[n][3] + bv.w, 0.f));
            int byte = r * 256 + n * 32 + g * 8;
            byte ^= ((r & 3) << 5) ^ ((r & 4) << 2);
            *(ushort4*)(hw + byte) = w;
        }
    };

    auto loadH = [&](short8* h4) {
        #pragma unroll
        for (int kt = 0; kt < 4; ++kt) {
            int byte = r * 256 + kt * 64 + g * 16;
            byte ^= ((r & 3) << 5) ^ ((r & 4) << 2);
            h4[kt] = *(const short8*)(hw + byte);
        }
    };

    auto storeG = [&](ushort* __restrict__ dst) {
        #pragma unroll
        for (int it = 0; it < 4; ++it) {
            int row  = it * 4 + g;
            int byte = row * 256 + (lane & 15) * 16;
            byte ^= ((row & 3) << 5) ^ ((row & 4) << 2);
            short8 v = *(const short8*)(hw + byte);
            *(short8*)&dst[(size_t)rowbase * EMB + row * EMB + (lane & 15) * 8] = v;
        }
    };

    short8 h4[4];

    stageW(0); __syncthreads();
    runMFMA(af); epi(b10); __syncthreads();
    stageW(1); loadH(h4); __syncthreads();
    runMFMA(h4); epi(b11); __syncthreads();
    stageW(2); storeG(X1b); __syncthreads();
    runMFMA(af); epi(b20); __syncthreads();
    stageW(3); loadH(h4); __syncthreads();
    runMFMA(h4); epi(b21); __syncthreads();
    storeG(X2b);
}

// ---------------------------------------------------------------------------
// gather_seg: one block (1024 thr) per segment. Stage entries in LDS,
// 64-bin counting sort (native int LDS atomics only), then 16 waves x 4 rows
// with REGISTER accumulators and 8-deep batched coalesced row gathers.
// ---------------------------------------------------------------------------
__global__ __launch_bounds__(1024, 2) void gather_seg(
    const ushort* __restrict__ X1b, const ushort* __restrict__ X2b,
    const unsigned long long* __restrict__ srt, const int* __restrict__ segptr,
    float* __restrict__ out)
{
    __shared__ unsigned long long ent[ENTCAP];      // 8 KB
    __shared__ unsigned long long sorted[ENTCAP];   // 8 KB
    __shared__ int hist[64];
    __shared__ int rptr[65];

    const int s   = blockIdx.x;
    const int tid = threadIdx.x;

    const int beg = segptr[s], end = segptr[s + 1];
    const int n  = end - beg;
    const int nl = n > ENTCAP ? ENTCAP : n;

    if (tid < 64) hist[tid] = 0;
    __syncthreads();

    // stage + histogram (int atomics: native ds_add)
    for (int i = tid; i < nl; i += 1024) {
        unsigned long long e = srt[beg + i];
        ent[i] = e;
        atomicAdd(&hist[(int)(e >> 34)], 1);
    }
    __syncthreads();

    // wave-0 shuffle scan of 64 bins
    if (tid < 64) {
        int c = hist[tid];
        int pfx = c;
        #pragma unroll
        for (int off = 1; off < 64; off <<= 1) {
            int v = __shfl_up(pfx, off, 64);
            if (tid >= off) pfx += v;
        }
        rptr[tid] = pfx - c;
        hist[tid] = pfx - c;                 // claim counters
        if (tid == 63) rptr[64] = pfx;
    }
    __syncthreads();

    // rank-scatter into row-grouped order (native int ds_add_rtn)
    for (int i = tid; i < nl; i += 1024) {
        unsigned long long e = ent[i];
        int p = atomicAdd(&hist[(int)(e >> 34)], 1);
        sorted[p] = e;
    }
    __syncthreads();

    // 16 waves x 4 rows, register accumulation, 8-deep coalesced gathers
    const int wv = tid >> 6, lane = tid & 63;
    const unsigned* x1 = (const unsigned*)X1b + lane;
    const unsigned* x2 = (const unsigned*)X2b + lane;

    #pragma unroll
    for (int rr = 0; rr < 4; ++rr) {
        const int row = wv * 4 + rr;
        const int rb = rptr[row], re = rptr[row + 1];
        float ax = 0.f, ay = 0.f;
        for (int c = rb; c < re; c += 8) {
            int m = re - c; if (m > 8) m = 8;
            unsigned long long E[8];
            #pragma unroll
            for (int e = 0; e < 8; ++e)
                E[e] = sorted[c + (e < m ? e : 0)];
            #pragma unroll
            for (int e = 0; e < 8; ++e) {
                unsigned u1 = x1[(unsigned)(E[e] & 0x1FFFF) * 64u];
                unsigned u2 = x2[(unsigned)((E[e] >> 17) & 0x1FFFF) * 64u];
                if (e >= m) u1 = 0u;
                ax += bfl(u1) * bfl(u2);
                ay += bfh(u1) * bfh(u2);
            }
        }
        if (n > ENTCAP) {                    // overflow fallback (never taken)
            for (int i = beg + ENTCAP; i < end; ++i) {
                unsigned long long e = srt[i];
                if ((int)(e >> 34) == row) {
                    unsigned u1 = x1[(unsigned)(e & 0x1FFFF) * 64u];
                    unsigned u2 = x2[(unsigned)((e >> 17) & 0x1FFFF) * 64u];
                    ax += bfl(u1) * bfl(u2);
                    ay += bfh(u1) * bfh(u2);
                }
            }
        }
        *(float2*)(out + ((size_t)s * SEGSZ + row) * EMB + lane * 2) =
            make_float2(ax, ay);
    }
}

// ---------------------------------------------------------------------------
extern "C" void kernel_launch(void* const* d_in, const int* in_sizes, int n_in,
                              void* d_out, int out_size, void* d_ws, size_t ws_size,
                              hipStream_t stream)
{
    (void)in_sizes; (void)n_in; (void)out_size; (void)ws_size;

    const float* Xv  = (const float*)d_in[0];
    const float* W10 = (const float*)d_in[1];
    const float* b10 = (const float*)d_in[2];
    const float* W11 = (const float*)d_in[3];
    const float* b11 = (const float*)d_in[4];
    const float* W20 = (const float*)d_in[5];
    const float* b20 = (const float*)d_in[6];
    const float* W21 = (const float*)d_in[7];
    const float* b21 = (const float*)d_in[8];
    const int*   ia  = (const int*)d_in[9];
    const int*   ib  = (const int*)d_in[10];
    const int*   io  = (const int*)d_in[11];
    float* out = (float*)d_out;

    char* ws = (char*)d_ws;
    ushort*             X1b    = (ushort*)(ws);                 // 32 MB
    ushort*             X2b    = (ushort*)(ws + 33554432);      // 32 MB
    ushort*             Wpk    = (ushort*)(ws + 67108864);      // 256 KB
    int*                bh     = (int*)(ws + 67371008);         // 2 MB
    int*                segptr = (int*)(ws + 69468160);         // 8.2 KB
    unsigned long long* srt    = (unsigned long long*)(ws + 69476864); // 8 MB

    prep_kernel<<<288, 256, 0, stream>>>(W10, W11, W20, W21, Wpk, io, bh);
    scan1_kernel<<<1, 1024, 0, stream>>>(bh, segptr);
    union_kernel<<<2080, 256, 0, stream>>>(Xv, Wpk, b10, b11, b20, b21,
                                           X1b, X2b, io, ia, ib, bh, srt);
    gather_seg<<<NSEG, 1024, 0, stream>>>(X1b, X2b, srt, segptr, out);
}

// Round 10
// 180.062 us; speedup vs baseline: 5.3490x; 2.0961x over previous
//
#include <hip/hip_runtime.h>
#include <hip/hip_bf16.h>

#define NNZ  131072
#define MT   1048576
#define EMB  128
#define NSEG 2048           // segments = io >> 6 (64 output rows each)
#define SEGSZ 64
#define ENTCAP 1024         // staged entries per segment (mean 512, +22 sigma)

typedef __attribute__((ext_vector_type(8))) short  short8;
typedef __attribute__((ext_vector_type(4))) float  floatx4;

__device__ __forceinline__ ushort f2bf(float f) {
    unsigned u = __float_as_uint(f);
    u = (u + 0x7FFFu + ((u >> 16) & 1u)) >> 16;   // RNE
    return (ushort)u;
}
__device__ __forceinline__ float bfl(unsigned u) { return __uint_as_float(u << 16); }
__device__ __forceinline__ float bfh(unsigned u) { return __uint_as_float(u & 0xffff0000u); }

__device__ __forceinline__ unsigned long long packE(int a, int b, int o) {
    return (unsigned long long)(unsigned)a |
           ((unsigned long long)(unsigned)b << 17) |
           ((unsigned long long)(unsigned)(o & 63) << 34);
}

// ---------------------------------------------------------------------------
// prep: blocks 0..31 pack weights; blocks 32..287 per-block 2048-bin
// histograms of io>>6 (4096 items each, LDS int atomics).
// ---------------------------------------------------------------------------
__global__ __launch_bounds__(256) void prep_kernel(
    const float* __restrict__ W10, const float* __restrict__ W11,
    const float* __restrict__ W20, const float* __restrict__ W21,
    ushort* __restrict__ Wpk, const int* __restrict__ io,
    int* __restrict__ bh)
{
    __shared__ int h[NSEG];
    const int bid = blockIdx.x, tid = threadIdx.x;

    if (bid < 32) {                          // ---- weight pack ----
        int s = bid * 256 + tid;             // 0..8191
        int L = s >> 11, sl = s & 2047;
        const float* W = (L == 0) ? W10 : (L == 1) ? W11 : (L == 2) ? W20 : W21;
        int lane = sl & 63, nk = sl >> 6;
        int col  = (nk >> 2) * 16 + (lane & 15);
        int krow = (nk & 3) * 32 + (lane >> 4) * 8;
        short8 w;
        #pragma unroll
        for (int j = 0; j < 8; ++j)
            w[j] = (short)f2bf(W[(krow + j) * EMB + col]);
        *(short8*)&Wpk[(size_t)s * 8] = w;
        return;
    }

    const int b = bid - 32;                  // 0..255
    for (int i = tid; i < NSEG; i += 256) h[i] = 0;
    __syncthreads();
    const int4* io4 = (const int4*)io + b * 1024;
    for (int j = tid; j < 1024; j += 256) {
        int4 v = io4[j];
        atomicAdd(&h[v.x >> 6], 1);
        atomicAdd(&h[v.y >> 6], 1);
        atomicAdd(&h[v.z >> 6], 1);
        atomicAdd(&h[v.w >> 6], 1);
    }
    __syncthreads();
    for (int d = tid; d < NSEG; d += 256) bh[d * 256 + b] = h[d];
}

// ---------------------------------------------------------------------------
// 3-phase multi-block scan (replaces the 210us single-block scan1):
// scanA: per-segment totals; scanB: single-block scan of 2048 totals ->
// segptr; scanC: within-segment 256-column scan, rebased, emitting the 32
// producer base columns into compact pb[NSEG*32].
// ---------------------------------------------------------------------------
__global__ __launch_bounds__(256) void scanA_kernel(
    const int* __restrict__ bh, int* __restrict__ segtot)
{
    __shared__ int r[4];
    const int d = blockIdx.x, tid = threadIdx.x;
    int v = bh[d * 256 + tid];
    #pragma unroll
    for (int off = 32; off; off >>= 1) v += __shfl_down(v, off, 64);
    if ((tid & 63) == 0) r[tid >> 6] = v;
    __syncthreads();
    if (tid == 0) segtot[d] = r[0] + r[1] + r[2] + r[3];
}

__global__ __launch_bounds__(1024) void scanB_kernel(
    const int* __restrict__ segtot, int* __restrict__ segptr)
{
    __shared__ int part[1024];
    const int tid = threadIdx.x;
    int a = segtot[tid * 2], b = segtot[tid * 2 + 1];
    int s = a + b;
    part[tid] = s;
    __syncthreads();
    for (int off = 1; off < 1024; off <<= 1) {
        int v = (tid >= off) ? part[tid - off] : 0;
        __syncthreads();
        part[tid] += v;
        __syncthreads();
    }
    int run = part[tid] - s;                 // exclusive
    segptr[tid * 2]     = run;
    segptr[tid * 2 + 1] = run + a;
    if (tid == 1023) segptr[NSEG] = run + s; // = MT
}

__global__ __launch_bounds__(256) void scanC_kernel(
    const int* __restrict__ bh, const int* __restrict__ segptr,
    int* __restrict__ pb)
{
    __shared__ int wsum[4];
    const int d = blockIdx.x, tid = threadIdx.x;
    int v = bh[d * 256 + tid];
    int pfx = v;
    #pragma unroll
    for (int off = 1; off < 64; off <<= 1) {
        int t = __shfl_up(pfx, off, 64);
        if ((tid & 63) >= off) pfx += t;
    }
    if ((tid & 63) == 63) wsum[tid >> 6] = pfx;
    __syncthreads();
    int wb = 0;
    #pragma unroll
    for (int w = 0; w < 4; ++w) if (w < (tid >> 6)) wb += wsum[w];
    int excl = segptr[d] + wb + pfx - v;     // exclusive prefix at column tid
    if ((tid & 7) == 0) pb[d * 32 + (tid >> 3)] = excl;
}

// ---------------------------------------------------------------------------
// Union: grid 2080 x 256. blockIdx%65==0 -> seg_scatter (32 blocks, each
// covers 32768 items; LDS rank-claim from pb bases); else -> mlp (2048).
// ---------------------------------------------------------------------------
__global__ __launch_bounds__(256, 3) void union_kernel(
    const float* __restrict__ Xv, const ushort* __restrict__ Wpk,
    const float* __restrict__ b10, const float* __restrict__ b11,
    const float* __restrict__ b20, const float* __restrict__ b21,
    ushort* __restrict__ X1b, ushort* __restrict__ X2b,
    const int* __restrict__ io, const int* __restrict__ ia,
    const int* __restrict__ ib, const int* __restrict__ pb,
    unsigned long long* __restrict__ srt)
{
    __shared__ ushort Wp[16384];           // 32 KB (scatter aliases 8 KB)
    __shared__ ushort Hs[8192];            // 16 KB

    const int bid = blockIdx.x;
    const int tid = threadIdx.x;
    const int q   = bid / 65;

    if (bid == q * 65) {                   // ---- scatter role (q in 0..31) ----
        int* cur = (int*)Wp;               // 2048 ints
        for (int d = tid; d < NSEG; d += 256) cur[d] = pb[d * 32 + q];
        __syncthreads();
        const int4* io4 = (const int4*)io + q * 8192;
        const int4* ia4 = (const int4*)ia + q * 8192;
        const int4* ib4 = (const int4*)ib + q * 8192;
        for (int j = tid; j < 8192; j += 256) {
            int4 o = io4[j], a = ia4[j], c = ib4[j];
            int p;
            p = atomicAdd(&cur[o.x >> 6], 1); srt[p] = packE(a.x, c.x, o.x);
            p = atomicAdd(&cur[o.y >> 6], 1); srt[p] = packE(a.y, c.y, o.y);
            p = atomicAdd(&cur[o.z >> 6], 1); srt[p] = packE(a.z, c.z, o.z);
            p = atomicAdd(&cur[o.w >> 6], 1); srt[p] = packE(a.w, c.w, o.w);
        }
        return;
    }

    // ---- mlp role ----
    const int mid  = bid - q - 1;          // dense 0..2047
    const int wave = tid >> 6;
    const int lane = tid & 63;
    const int g    = lane >> 4;
    const int r    = lane & 15;
    const int rowbase = mid * 64 + wave * 16;
    char* hw = (char*)(Hs + wave * 2048);

    short8 af[4];
    {
        const float* xsrc = Xv + (size_t)(rowbase + r) * EMB;
        #pragma unroll
        for (int kt = 0; kt < 4; ++kt) {
            const float4* p = (const float4*)(xsrc + kt * 32 + g * 8);
            float4 v0 = p[0], v1 = p[1];
            short8 a;
            a[0] = (short)f2bf(v0.x); a[1] = (short)f2bf(v0.y);
            a[2] = (short)f2bf(v0.z); a[3] = (short)f2bf(v0.w);
            a[4] = (short)f2bf(v1.x); a[5] = (short)f2bf(v1.y);
            a[6] = (short)f2bf(v1.z); a[7] = (short)f2bf(v1.w);
            af[kt] = a;
        }
    }

    auto stageW = [&](int L) {
        const ushort* src = Wpk + (size_t)L * 16384;
        #pragma unroll
        for (int s = tid; s < 2048; s += 256)
            *(short8*)&Wp[s * 8] = *(const short8*)&src[(size_t)s * 8];
    };

    floatx4 acc[8];
    auto runMFMA = [&](const short8* a4) {
        #pragma unroll
        for (int n = 0; n < 8; ++n) {
            floatx4 c = {0.f, 0.f, 0.f, 0.f};
            #pragma unroll
            for (int kt = 0; kt < 4; ++kt) {
                short8 b = *(const short8*)&Wp[((n * 4 + kt) * 64 + lane) * 8];
                c = __builtin_amdgcn_mfma_f32_16x16x32_bf16(b, a4[kt], c, 0, 0, 0);
            }
            acc[n] = c;
        }
    };

    auto epi = [&](const float* __restrict__ bias) {
        #pragma unroll
        for (int n = 0; n < 8; ++n) {
            float4 bv = *(const float4*)&bias[n * 16 + g * 4];
            ushort4 w;
            w.x = f2bf(fmaxf(acc[n][0] + bv.x, 0.f));
            w.y = f2bf(fmaxf(acc[n][1] + bv.y, 0.f));
            w.z = f2bf(fmaxf(acc[n][2] + bv.z, 0.f));
            w.w = f2bf(fmaxf(acc[n][3] + bv.w, 0.f));
            int byte = r * 256 + n * 32 + g * 8;
            byte ^= ((r & 3) << 5) ^ ((r & 4) << 2);
            *(ushort4*)(hw + byte) = w;
        }
    };

    auto loadH = [&](short8* h4) {
        #pragma unroll
        for (int kt = 0; kt < 4; ++kt) {
            int byte = r * 256 + kt * 64 + g * 16;
            byte ^= ((r & 3) << 5) ^ ((r & 4) << 2);
            h4[kt] = *(const short8*)(hw + byte);
        }
    };

    auto storeG = [&](ushort* __restrict__ dst) {
        #pragma unroll
        for (int it = 0; it < 4; ++it) {
            int row  = it * 4 + g;
            int byte = row * 256 + (lane & 15) * 16;
            byte ^= ((row & 3) << 5) ^ ((row & 4) << 2);
            short8 v = *(const short8*)(hw + byte);
            *(short8*)&dst[(size_t)rowbase * EMB + row * EMB + (lane & 15) * 8] = v;
        }
    };

    short8 h4[4];

    stageW(0); __syncthreads();
    runMFMA(af); epi(b10); __syncthreads();
    stageW(1); loadH(h4); __syncthreads();
    runMFMA(h4); epi(b11); __syncthreads();
    stageW(2); storeG(X1b); __syncthreads();
    runMFMA(af); epi(b20); __syncthreads();
    stageW(3); loadH(h4); __syncthreads();
    runMFMA(h4); epi(b21); __syncthreads();
    storeG(X2b);
}

// ---------------------------------------------------------------------------
// gather_seg: one block (1024 thr) per segment. Stage entries in LDS,
// 64-bin counting sort (native int LDS atomics only), then 16 waves x 4 rows
// with REGISTER accumulators and 8-deep batched coalesced row gathers.
// ---------------------------------------------------------------------------
__global__ __launch_bounds__(1024, 2) void gather_seg(
    const ushort* __restrict__ X1b, const ushort* __restrict__ X2b,
    const unsigned long long* __restrict__ srt, const int* __restrict__ segptr,
    float* __restrict__ out)
{
    __shared__ unsigned long long ent[ENTCAP];      // 8 KB
    __shared__ unsigned long long sorted[ENTCAP];   // 8 KB
    __shared__ int hist[64];
    __shared__ int rptr[65];

    const int s   = blockIdx.x;
    const int tid = threadIdx.x;

    const int beg = segptr[s], end = segptr[s + 1];
    const int n  = end - beg;
    const int nl = n > ENTCAP ? ENTCAP : n;

    if (tid < 64) hist[tid] = 0;
    __syncthreads();

    // stage + histogram (int atomics: native ds_add)
    for (int i = tid; i < nl; i += 1024) {
        unsigned long long e = srt[beg + i];
        ent[i] = e;
        atomicAdd(&hist[(int)(e >> 34)], 1);
    }
    __syncthreads();

    // wave-0 shuffle scan of 64 bins
    if (tid < 64) {
        int c = hist[tid];
        int pfx = c;
        #pragma unroll
        for (int off = 1; off < 64; off <<= 1) {
            int v = __shfl_up(pfx, off, 64);
            if (tid >= off) pfx += v;
        }
        rptr[tid] = pfx - c;
        hist[tid] = pfx - c;                 // claim counters
        if (tid == 63) rptr[64] = pfx;
    }
    __syncthreads();

    // rank-scatter into row-grouped order (native int ds_add_rtn)
    for (int i = tid; i < nl; i += 1024) {
        unsigned long long e = ent[i];
        int p = atomicAdd(&hist[(int)(e >> 34)], 1);
        sorted[p] = e;
    }
    __syncthreads();

    // 16 waves x 4 rows, register accumulation, 8-deep coalesced gathers
    const int wv = tid >> 6, lane = tid & 63;
    const unsigned* x1 = (const unsigned*)X1b + lane;
    const unsigned* x2 = (const unsigned*)X2b + lane;

    #pragma unroll
    for (int rr = 0; rr < 4; ++rr) {
        const int row = wv * 4 + rr;
        const int rb = rptr[row], re = rptr[row + 1];
        float ax = 0.f, ay = 0.f;
        for (int c = rb; c < re; c += 8) {
            int m = re - c; if (m > 8) m = 8;
            unsigned long long E[8];
            #pragma unroll
            for (int e = 0; e < 8; ++e)
                E[e] = sorted[c + (e < m ? e : 0)];
            #pragma unroll
            for (int e = 0; e < 8; ++e) {
                unsigned u1 = x1[(unsigned)(E[e] & 0x1FFFF) * 64u];
                unsigned u2 = x2[(unsigned)((E[e] >> 17) & 0x1FFFF) * 64u];
                if (e >= m) u1 = 0u;
                ax += bfl(u1) * bfl(u2);
                ay += bfh(u1) * bfh(u2);
            }
        }
        if (n > ENTCAP) {                    // overflow fallback (never taken)
            for (int i = beg + ENTCAP; i < end; ++i) {
                unsigned long long e = srt[i];
                if ((int)(e >> 34) == row) {
                    unsigned u1 = x1[(unsigned)(e & 0x1FFFF) * 64u];
                    unsigned u2 = x2[(unsigned)((e >> 17) & 0x1FFFF) * 64u];
                    ax += bfl(u1) * bfl(u2);
                    ay += bfh(u1) * bfh(u2);
                }
            }
        }
        *(float2*)(out + ((size_t)s * SEGSZ + row) * EMB + lane * 2) =
            make_float2(ax, ay);
    }
}

// ---------------------------------------------------------------------------
extern "C" void kernel_launch(void* const* d_in, const int* in_sizes, int n_in,
                              void* d_out, int out_size, void* d_ws, size_t ws_size,
                              hipStream_t stream)
{
    (void)in_sizes; (void)n_in; (void)out_size; (void)ws_size;

    const float* Xv  = (const float*)d_in[0];
    const float* W10 = (const float*)d_in[1];
    const float* b10 = (const float*)d_in[2];
    const float* W11 = (const float*)d_in[3];
    const float* b11 = (const float*)d_in[4];
    const float* W20 = (const float*)d_in[5];
    const float* b20 = (const float*)d_in[6];
    const float* W21 = (const float*)d_in[7];
    const float* b21 = (const float*)d_in[8];
    const int*   ia  = (const int*)d_in[9];
    const int*   ib  = (const int*)d_in[10];
    const int*   io  = (const int*)d_in[11];
    float* out = (float*)d_out;

    char* ws = (char*)d_ws;
    ushort*             X1b    = (ushort*)(ws);                 // 32 MB
    ushort*             X2b    = (ushort*)(ws + 33554432);      // 32 MB
    ushort*             Wpk    = (ushort*)(ws + 67108864);      // 256 KB
    int*                bh     = (int*)(ws + 67371008);         // 2 MB
    int*                segptr = (int*)(ws + 69468160);         // 16 KB slot
    int*                segtot = (int*)(ws + 69484544);         // 16 KB slot
    int*                pb     = (int*)(ws + 69500928);         // 256 KB
    unsigned long long* srt    = (unsigned long long*)(ws + 69763072); // 8 MB

    prep_kernel<<<288, 256, 0, stream>>>(W10, W11, W20, W21, Wpk, io, bh);
    scanA_kernel<<<NSEG, 256, 0, stream>>>(bh, segtot);
    scanB_kernel<<<1, 1024, 0, stream>>>(segtot, segptr);
    scanC_kernel<<<NSEG, 256, 0, stream>>>(bh, segptr, pb);
    union_kernel<<<2080, 256, 0, stream>>>(Xv, Wpk, b10, b11, b20, b21,
                                           X1b, X2b, io, ia, ib, pb, srt);
    gather_seg<<<NSEG, 1024, 0, stream>>>(X1b, X2b, srt, segptr, out);
}

// Round 11
// 156.365 us; speedup vs baseline: 6.1596x; 1.1515x over previous
//
#include <hip/hip_runtime.h>
#include <hip/hip_bf16.h>

#define NNZ  131072
#define MT   1048576
#define EMB  128
#define NSEG 2048           // segments = io >> 6 (64 output rows each)
#define SEGSZ 64
#define ENTCAP 1024         // staged entries per segment (mean 512, +22 sigma)

typedef __attribute__((ext_vector_type(8))) short  short8;
typedef __attribute__((ext_vector_type(4))) float  floatx4;

__device__ __forceinline__ ushort f2bf(float f) {
    unsigned u = __float_as_uint(f);
    u = (u + 0x7FFFu + ((u >> 16) & 1u)) >> 16;   // RNE
    return (ushort)u;
}
__device__ __forceinline__ float bfl(unsigned u) { return __uint_as_float(u << 16); }
__device__ __forceinline__ float bfh(unsigned u) { return __uint_as_float(u & 0xffff0000u); }

__device__ __forceinline__ unsigned long long packE(int a, int b, int o) {
    return (unsigned long long)(unsigned)a |
           ((unsigned long long)(unsigned)b << 17) |
           ((unsigned long long)(unsigned)(o & 63) << 34);
}

// ---------------------------------------------------------------------------
// prep: blocks 0..31 pack weights; blocks 32..287 per-block 2048-bin
// histograms of io>>6 (4096 items each, LDS int atomics).
// ---------------------------------------------------------------------------
__global__ __launch_bounds__(256) void prep_kernel(
    const float* __restrict__ W10, const float* __restrict__ W11,
    const float* __restrict__ W20, const float* __restrict__ W21,
    ushort* __restrict__ Wpk, const int* __restrict__ io,
    int* __restrict__ bh)
{
    __shared__ int h[NSEG];
    const int bid = blockIdx.x, tid = threadIdx.x;

    if (bid < 32) {                          // ---- weight pack ----
        int s = bid * 256 + tid;             // 0..8191
        int L = s >> 11, sl = s & 2047;
        const float* W = (L == 0) ? W10 : (L == 1) ? W11 : (L == 2) ? W20 : W21;
        int lane = sl & 63, nk = sl >> 6;
        int col  = (nk >> 2) * 16 + (lane & 15);
        int krow = (nk & 3) * 32 + (lane >> 4) * 8;
        short8 w;
        #pragma unroll
        for (int j = 0; j < 8; ++j)
            w[j] = (short)f2bf(W[(krow + j) * EMB + col]);
        *(short8*)&Wpk[(size_t)s * 8] = w;
        return;
    }

    const int b = bid - 32;                  // 0..255
    for (int i = tid; i < NSEG; i += 256) h[i] = 0;
    __syncthreads();
    const int4* io4 = (const int4*)io + b * 1024;
    for (int j = tid; j < 1024; j += 256) {
        int4 v = io4[j];
        atomicAdd(&h[v.x >> 6], 1);
        atomicAdd(&h[v.y >> 6], 1);
        atomicAdd(&h[v.z >> 6], 1);
        atomicAdd(&h[v.w >> 6], 1);
    }
    __syncthreads();
    for (int d = tid; d < NSEG; d += 256) bh[d * 256 + b] = h[d];
}

// ---------------------------------------------------------------------------
// 3-phase multi-block scan. scanA: per-segment totals. scanB: scan of 2048
// totals -> segptr. scanC: within-segment 256-column exclusive scan, rebased
// by segptr, written back into bh IN PLACE (full 256 producer columns).
// ---------------------------------------------------------------------------
__global__ __launch_bounds__(256) void scanA_kernel(
    const int* __restrict__ bh, int* __restrict__ segtot)
{
    __shared__ int r[4];
    const int d = blockIdx.x, tid = threadIdx.x;
    int v = bh[d * 256 + tid];
    #pragma unroll
    for (int off = 32; off; off >>= 1) v += __shfl_down(v, off, 64);
    if ((tid & 63) == 0) r[tid >> 6] = v;
    __syncthreads();
    if (tid == 0) segtot[d] = r[0] + r[1] + r[2] + r[3];
}

__global__ __launch_bounds__(1024) void scanB_kernel(
    const int* __restrict__ segtot, int* __restrict__ segptr)
{
    __shared__ int part[1024];
    const int tid = threadIdx.x;
    int a = segtot[tid * 2], b = segtot[tid * 2 + 1];
    int s = a + b;
    part[tid] = s;
    __syncthreads();
    for (int off = 1; off < 1024; off <<= 1) {
        int v = (tid >= off) ? part[tid - off] : 0;
        __syncthreads();
        part[tid] += v;
        __syncthreads();
    }
    int run = part[tid] - s;                 // exclusive
    segptr[tid * 2]     = run;
    segptr[tid * 2 + 1] = run + a;
    if (tid == 1023) segptr[NSEG] = run + s; // = MT
}

__global__ __launch_bounds__(256) void scanC_kernel(
    int* __restrict__ bh, const int* __restrict__ segptr)
{
    __shared__ int wsum[4];
    const int d = blockIdx.x, tid = threadIdx.x;
    int v = bh[d * 256 + tid];
    int pfx = v;
    #pragma unroll
    for (int off = 1; off < 64; off <<= 1) {
        int t = __shfl_up(pfx, off, 64);
        if ((tid & 63) >= off) pfx += t;
    }
    if ((tid & 63) == 63) wsum[tid >> 6] = pfx;
    __syncthreads();
    int wb = 0;
    #pragma unroll
    for (int w = 0; w < 4; ++w) if (w < (tid >> 6)) wb += wsum[w];
    bh[d * 256 + tid] = segptr[d] + wb + pfx - v;   // exclusive, rebased
}

// ---------------------------------------------------------------------------
// Union: grid 2304 x 256. blockIdx%9==0 -> seg_scatter (256 blocks x 4096
// items, LDS rank-claim from scanned bh columns, zero global atomics);
// else -> mlp (2048 blocks, 64 rows each).
// ---------------------------------------------------------------------------
__global__ __launch_bounds__(256, 3) void union_kernel(
    const float* __restrict__ Xv, const ushort* __restrict__ Wpk,
    const float* __restrict__ b10, const float* __restrict__ b11,
    const float* __restrict__ b20, const float* __restrict__ b21,
    ushort* __restrict__ X1b, ushort* __restrict__ X2b,
    const int* __restrict__ io, const int* __restrict__ ia,
    const int* __restrict__ ib, const int* __restrict__ bh,
    unsigned long long* __restrict__ srt)
{
    __shared__ ushort Wp[16384];           // 32 KB (scatter aliases 8 KB)
    __shared__ ushort Hs[8192];            // 16 KB

    const int bid = blockIdx.x;
    const int tid = threadIdx.x;
    const int q   = bid / 9;

    if (bid == q * 9) {                    // ---- scatter role (q in 0..255) ----
        int* cur = (int*)Wp;               // 2048 ints
        for (int d = tid; d < NSEG; d += 256) cur[d] = bh[d * 256 + q];
        __syncthreads();
        const int4* io4 = (const int4*)io + q * 1024;
        const int4* ia4 = (const int4*)ia + q * 1024;
        const int4* ib4 = (const int4*)ib + q * 1024;
        for (int j = tid; j < 1024; j += 256) {
            int4 o = io4[j], a = ia4[j], c = ib4[j];
            int p;
            p = atomicAdd(&cur[o.x >> 6], 1); srt[p] = packE(a.x, c.x, o.x);
            p = atomicAdd(&cur[o.y >> 6], 1); srt[p] = packE(a.y, c.y, o.y);
            p = atomicAdd(&cur[o.z >> 6], 1); srt[p] = packE(a.z, c.z, o.z);
            p = atomicAdd(&cur[o.w >> 6], 1); srt[p] = packE(a.w, c.w, o.w);
        }
        return;
    }

    // ---- mlp role ----
    const int mid  = bid - q - 1;          // dense 0..2047
    const int wave = tid >> 6;
    const int lane = tid & 63;
    const int g    = lane >> 4;
    const int r    = lane & 15;
    const int rowbase = mid * 64 + wave * 16;
    char* hw = (char*)(Hs + wave * 2048);

    short8 af[4];
    {
        const float* xsrc = Xv + (size_t)(rowbase + r) * EMB;
        #pragma unroll
        for (int kt = 0; kt < 4; ++kt) {
            const float4* p = (const float4*)(xsrc + kt * 32 + g * 8);
            float4 v0 = p[0], v1 = p[1];
            short8 a;
            a[0] = (short)f2bf(v0.x); a[1] = (short)f2bf(v0.y);
            a[2] = (short)f2bf(v0.z); a[3] = (short)f2bf(v0.w);
            a[4] = (short)f2bf(v1.x); a[5] = (short)f2bf(v1.y);
            a[6] = (short)f2bf(v1.z); a[7] = (short)f2bf(v1.w);
            af[kt] = a;
        }
    }

    auto stageW = [&](int L) {
        const ushort* src = Wpk + (size_t)L * 16384;
        #pragma unroll
        for (int s = tid; s < 2048; s += 256)
            *(short8*)&Wp[s * 8] = *(const short8*)&src[(size_t)s * 8];
    };

    floatx4 acc[8];
    auto runMFMA = [&](const short8* a4) {
        #pragma unroll
        for (int n = 0; n < 8; ++n) {
            floatx4 c = {0.f, 0.f, 0.f, 0.f};
            #pragma unroll
            for (int kt = 0; kt < 4; ++kt) {
                short8 b = *(const short8*)&Wp[((n * 4 + kt) * 64 + lane) * 8];
                c = __builtin_amdgcn_mfma_f32_16x16x32_bf16(b, a4[kt], c, 0, 0, 0);
            }
            acc[n] = c;
        }
    };

    auto epi = [&](const float* __restrict__ bias) {
        #pragma unroll
        for (int n = 0; n < 8; ++n) {
            float4 bv = *(const float4*)&bias[n * 16 + g * 4];
            ushort4 w;
            w.x = f2bf(fmaxf(acc[n][0] + bv.x, 0.f));
            w.y = f2bf(fmaxf(acc[n][1] + bv.y, 0.f));
            w.z = f2bf(fmaxf(acc[n][2] + bv.z, 0.f));
            w.w = f2bf(fmaxf(acc[n][3] + bv.w, 0.f));
            int byte = r * 256 + n * 32 + g * 8;
            byte ^= ((r & 3) << 5) ^ ((r & 4) << 2);
            *(ushort4*)(hw + byte) = w;
        }
    };

    auto loadH = [&](short8* h4) {
        #pragma unroll
        for (int kt = 0; kt < 4; ++kt) {
            int byte = r * 256 + kt * 64 + g * 16;
            byte ^= ((r & 3) << 5) ^ ((r & 4) << 2);
            h4[kt] = *(const short8*)(hw + byte);
        }
    };

    auto storeG = [&](ushort* __restrict__ dst) {
        #pragma unroll
        for (int it = 0; it < 4; ++it) {
            int row  = it * 4 + g;
            int byte = row * 256 + (lane & 15) * 16;
            byte ^= ((row & 3) << 5) ^ ((row & 4) << 2);
            short8 v = *(const short8*)(hw + byte);
            *(short8*)&dst[(size_t)rowbase * EMB + row * EMB + (lane & 15) * 8] = v;
        }
    };

    short8 h4[4];

    stageW(0); __syncthreads();
    runMFMA(af); epi(b10); __syncthreads();
    stageW(1); loadH(h4); __syncthreads();
    runMFMA(h4); epi(b11); __syncthreads();
    stageW(2); storeG(X1b); __syncthreads();
    runMFMA(af); epi(b20); __syncthreads();
    stageW(3); loadH(h4); __syncthreads();
    runMFMA(h4); epi(b21); __syncthreads();
    storeG(X2b);
}

// ---------------------------------------------------------------------------
// gather_seg: one block (1024 thr) per segment. Stage entries in LDS,
// 64-bin counting sort (native int LDS atomics only), then 16 waves x 4 rows
// with REGISTER accumulators and 8-deep batched coalesced row gathers.
// ---------------------------------------------------------------------------
__global__ __launch_bounds__(1024, 2) void gather_seg(
    const ushort* __restrict__ X1b, const ushort* __restrict__ X2b,
    const unsigned long long* __restrict__ srt, const int* __restrict__ segptr,
    float* __restrict__ out)
{
    __shared__ unsigned long long ent[ENTCAP];      // 8 KB
    __shared__ unsigned long long sorted[ENTCAP];   // 8 KB
    __shared__ int hist[64];
    __shared__ int rptr[65];

    const int s   = blockIdx.x;
    const int tid = threadIdx.x;

    const int beg = segptr[s], end = segptr[s + 1];
    const int n  = end - beg;
    const int nl = n > ENTCAP ? ENTCAP : n;

    if (tid < 64) hist[tid] = 0;
    __syncthreads();

    // stage + histogram (int atomics: native ds_add)
    for (int i = tid; i < nl; i += 1024) {
        unsigned long long e = srt[beg + i];
        ent[i] = e;
        atomicAdd(&hist[(int)(e >> 34)], 1);
    }
    __syncthreads();

    // wave-0 shuffle scan of 64 bins
    if (tid < 64) {
        int c = hist[tid];
        int pfx = c;
        #pragma unroll
        for (int off = 1; off < 64; off <<= 1) {
            int v = __shfl_up(pfx, off, 64);
            if (tid >= off) pfx += v;
        }
        rptr[tid] = pfx - c;
        hist[tid] = pfx - c;                 // claim counters
        if (tid == 63) rptr[64] = pfx;
    }
    __syncthreads();

    // rank-scatter into row-grouped order (native int ds_add_rtn)
    for (int i = tid; i < nl; i += 1024) {
        unsigned long long e = ent[i];
        int p = atomicAdd(&hist[(int)(e >> 34)], 1);
        sorted[p] = e;
    }
    __syncthreads();

    // 16 waves x 4 rows, register accumulation, 8-deep coalesced gathers
    const int wv = tid >> 6, lane = tid & 63;
    const unsigned* x1 = (const unsigned*)X1b + lane;
    const unsigned* x2 = (const unsigned*)X2b + lane;

    #pragma unroll
    for (int rr = 0; rr < 4; ++rr) {
        const int row = wv * 4 + rr;
        const int rb = rptr[row], re = rptr[row + 1];
        float ax = 0.f, ay = 0.f;
        for (int c = rb; c < re; c += 8) {
            int m = re - c; if (m > 8) m = 8;
            unsigned long long E[8];
            #pragma unroll
            for (int e = 0; e < 8; ++e)
                E[e] = sorted[c + (e < m ? e : 0)];
            #pragma unroll
            for (int e = 0; e < 8; ++e) {
                unsigned u1 = x1[(unsigned)(E[e] & 0x1FFFF) * 64u];
                unsigned u2 = x2[(unsigned)((E[e] >> 17) & 0x1FFFF) * 64u];
                if (e >= m) u1 = 0u;
                ax += bfl(u1) * bfl(u2);
                ay += bfh(u1) * bfh(u2);
            }
        }
        if (n > ENTCAP) {                    // overflow fallback (never taken)
            for (int i = beg + ENTCAP; i < end; ++i) {
                unsigned long long e = srt[i];
                if ((int)(e >> 34) == row) {
                    unsigned u1 = x1[(unsigned)(e & 0x1FFFF) * 64u];
                    unsigned u2 = x2[(unsigned)((e >> 17) & 0x1FFFF) * 64u];
                    ax += bfl(u1) * bfl(u2);
                    ay += bfh(u1) * bfh(u2);
                }
            }
        }
        *(float2*)(out + ((size_t)s * SEGSZ + row) * EMB + lane * 2) =
            make_float2(ax, ay);
    }
}

// ---------------------------------------------------------------------------
extern "C" void kernel_launch(void* const* d_in, const int* in_sizes, int n_in,
                              void* d_out, int out_size, void* d_ws, size_t ws_size,
                              hipStream_t stream)
{
    (void)in_sizes; (void)n_in; (void)out_size; (void)ws_size;

    const float* Xv  = (const float*)d_in[0];
    const float* W10 = (const float*)d_in[1];
    const float* b10 = (const float*)d_in[2];
    const float* W11 = (const float*)d_in[3];
    const float* b11 = (const float*)d_in[4];
    const float* W20 = (const float*)d_in[5];
    const float* b20 = (const float*)d_in[6];
    const float* W21 = (const float*)d_in[7];
    const float* b21 = (const float*)d_in[8];
    const int*   ia  = (const int*)d_in[9];
    const int*   ib  = (const int*)d_in[10];
    const int*   io  = (const int*)d_in[11];
    float* out = (float*)d_out;

    char* ws = (char*)d_ws;
    ushort*             X1b    = (ushort*)(ws);                 // 32 MB
    ushort*             X2b    = (ushort*)(ws + 33554432);      // 32 MB
    ushort*             Wpk    = (ushort*)(ws + 67108864);      // 256 KB
    int*                bh     = (int*)(ws + 67371008);         // 2 MB
    int*                segptr = (int*)(ws + 69468160);         // 16 KB slot
    int*                segtot = (int*)(ws + 69484544);         // 16 KB slot
    unsigned long long* srt    = (unsigned long long*)(ws + 69763072); // 8 MB

    prep_kernel<<<288, 256, 0, stream>>>(W10, W11, W20, W21, Wpk, io, bh);
    scanA_kernel<<<NSEG, 256, 0, stream>>>(bh, segtot);
    scanB_kernel<<<1, 1024, 0, stream>>>(segtot, segptr);
    scanC_kernel<<<NSEG, 256, 0, stream>>>(bh, segptr);
    union_kernel<<<2304, 256, 0, stream>>>(Xv, Wpk, b10, b11, b20, b21,
                                           X1b, X2b, io, ia, ib, bh, srt);
    gather_seg<<<NSEG, 1024, 0, stream>>>(X1b, X2b, srt, segptr, out);
}